// Round 4
// baseline (304.435 us; speedup 1.0000x reference)
//
#include <hip/hip_runtime.h>

// CIN (xDeepFM) fused kernel for MI355X (gfx950), bf16 MFMA path, round 4.
// 512-thread blocks (8 waves), 512 blocks, 2 blocks/CU -> 16 waves/CU (50% occ).
// L0: M=256 split 8 waves x 32 rows; in-register z-frags; barrier-free K-loop.
// L1: reassociated out1[o,c] = sum_m x[m,c]*(W1_m @ h)[o,c]; 8 waves = 4 row-groups
//     x 2 K-halves (keeps VGPR<=128); halves combined via LDS at the end.

typedef __bf16 bf16x8 __attribute__((ext_vector_type(8)));
typedef float f32x4 __attribute__((ext_vector_type(4)));

#define NB 2
#define NBLK 512
#define THREADS 512
#define K0STEPS 50   // 50*32 = 1600; rows with m==39 are zero-padded

__global__ __launch_bounds__(256) void prep_kernel(
    const float* __restrict__ w0, const float* __restrict__ w1,
    __bf16* __restrict__ w0b, __bf16* __restrict__ w1p) {
  int stride = gridDim.x * blockDim.x;
  int tid = blockIdx.x * blockDim.x + threadIdx.x;
  // w0b[blk][o][j]: K reordered as i' = m*40 + n (n<39 valid, else 0); i'>=1560 -> 0
  const int n0 = K0STEPS * 256 * 32;
  for (int idx = tid; idx < n0; idx += stride) {
    int j = idx & 31, o = (idx >> 5) & 255, blk = idx >> 13;
    int ip = blk * 32 + j;
    float v = 0.f;
    if (ip < 1560) {
      unsigned m = (unsigned)ip / 40u;
      unsigned n = (unsigned)ip - m * 40u;
      if (n < 39u) v = w0[o * 1521 + m * 39 + n];
    }
    w0b[idx] = (__bf16)v;
  }
  // w1p[((m*4+ks)*128 + o)*32 + j] = w1[o][m*128 + ks*32 + j]
  const int n1 = 39 * 4 * 128 * 32;
  for (int idx = tid; idx < n1; idx += stride) {
    int j = idx & 31, o = (idx >> 5) & 127, q = idx >> 12;
    int ks = q & 3, m = q >> 2;
    w1p[idx] = (__bf16)w1[o * 4992 + m * 128 + ks * 32 + j];
  }
}

__global__ __launch_bounds__(512, 4) void cin_kernel(
    const float* __restrict__ x,
    const __bf16* __restrict__ w0b, const float* __restrict__ b0,
    const __bf16* __restrict__ w1p, const float* __restrict__ b1,
    float* __restrict__ out) {
  // LDS: 5120 + 17408 + 33280 = 55808 B -> 2 blocks/CU
  __shared__ __align__(16) __bf16 xs[NB * 32 * 40];    // [c=(b,d)][40] (m=39 slot zero)
  __shared__ __align__(16) __bf16 h1[NB * 32 * 136];   // [c][136] h1a (bf16)
  __shared__ __align__(16) float red[4 * 32 * 65];     // K-half exchange, row pad 65

  const int t = threadIdx.x;
  const int bb = blockIdx.x * NB;
  const int w = t >> 6;          // wave id 0..7
  const int l15 = t & 15;
  const int lhi = (t >> 4) & 3;

  // ---- load x[b] -> xs transposed [c][m], bf16 ----
  for (int idx = t; idx < NB * 39 * 32; idx += THREADS) {
    int b = idx / 1248; int rem = idx - b * 1248;
    int m = rem >> 5; int d = rem & 31;
    xs[(b * 32 + d) * 40 + m] = (__bf16)x[(bb + b) * 1248 + rem];
  }
  if (t < NB * 32) xs[t * 40 + 39] = (__bf16)0.f;  // zero the m=39 pad
  __syncthreads();

  // ================= LAYER 0 (barrier-free K-loop, 32 rows/wave) =================
  f32x4 acc[2][4] = {};

  auto loadA0 = [&](int s, bf16x8 (&af)[2]) {
#pragma unroll
    for (int mt = 0; mt < 2; ++mt) {
      int o = w * 32 + mt * 16 + l15;
      af[mt] = *(const bf16x8*)(w0b + s * 8192 + o * 32 + lhi * 8);
    }
  };
  // per-wave in-register B fragments: bz[nt] holds z[k=i0..i0+7][c=nt*16+l15]
  auto zfr = [&](int s, bf16x8 (&bz)[4]) {
    unsigned i0 = (unsigned)(s * 32) + (unsigned)lhi * 8u;
    unsigned m = (i0 * 52429u) >> 21;   // i0/40 (exact for i0 < 2^16)
    unsigned nb = i0 - m * 40u;
#pragma unroll
    for (int nt = 0; nt < 4; ++nt) {
      int c = nt * 16 + l15;
      float xm = (float)xs[c * 40 + m];             // m==39 -> 0
      bf16x8 xn = *(const bf16x8*)&xs[c * 40 + nb]; // 16B-aligned
      bf16x8 vz;
#pragma unroll
      for (int j = 0; j < 8; ++j) vz[j] = (__bf16)(xm * (float)xn[j]);
      bz[nt] = vz;
    }
  };
  auto comp0 = [&](bf16x8 (&af)[2], bf16x8 (&bz)[4]) {
#pragma unroll
    for (int mt = 0; mt < 2; ++mt)
#pragma unroll
      for (int nt = 0; nt < 4; ++nt)
        acc[mt][nt] = __builtin_amdgcn_mfma_f32_16x16x32_bf16(af[mt], bz[nt], acc[mt][nt], 0, 0, 0);
  };

  {
    bf16x8 afA[2], afB[2];
    loadA0(0, afA);
    loadA0(1, afB);
    for (int s = 0; s < K0STEPS; s += 2) {
      bf16x8 bzA[4], bzB[4];
      zfr(s, bzA);
      comp0(afA, bzA);
      if (s + 2 < K0STEPS) loadA0(s + 2, afA);
      zfr(s + 1, bzB);
      comp0(afB, bzB);
      if (s + 3 < K0STEPS) loadA0(s + 3, afB);
    }
  }

  // ---- epilogue 0: bias+relu; o<128 -> h1a LDS; o>=128 -> d-sum -> out[ch 0..127]
  if (w < 4) {
#pragma unroll
    for (int mt = 0; mt < 2; ++mt) {
#pragma unroll
      for (int nt = 0; nt < 4; ++nt) {
        int c = nt * 16 + l15;
        int hbase = c * 136;
#pragma unroll
        for (int r = 0; r < 4; ++r) {
          int o = w * 32 + mt * 16 + lhi * 4 + r;
          float v = fmaxf(acc[mt][nt][r] + b0[o], 0.f);
          h1[hbase + o] = (__bf16)v;
        }
      }
    }
  } else {
#pragma unroll
    for (int mt = 0; mt < 2; ++mt) {
#pragma unroll
      for (int r = 0; r < 4; ++r) {
        int o = w * 32 + mt * 16 + lhi * 4 + r;  // 128..255
        float bias = b0[o];
        float sb0 = 0.f, sb1 = 0.f;
#pragma unroll
        for (int nt = 0; nt < 4; ++nt) {
          float v = fmaxf(acc[mt][nt][r] + bias, 0.f);
          v += __shfl_xor(v, 1); v += __shfl_xor(v, 2);
          v += __shfl_xor(v, 4); v += __shfl_xor(v, 8);
          if (nt < 2) sb0 += v; else sb1 += v;
        }
        if (l15 == 0) {
          out[(bb + 0) * 256 + (o - 128)] = sb0;
          out[(bb + 1) * 256 + (o - 128)] = sb1;
        }
      }
    }
  }
  __syncthreads();  // h1a visible to all waves

  // ============ LAYER 1 (reassociated; 4 row-groups x 2 K-halves) ============
  const int rt = w >> 1;   // row group: rows rt*32 .. rt*32+31
  const int kh = w & 1;    // K half: k in [kh*64, kh*64+64)

  // hf[kf][nt]: persistent B fragments of h for this K-half (32 VGPRs)
  bf16x8 hf[2][4];
#pragma unroll
  for (int kf = 0; kf < 2; ++kf)
#pragma unroll
    for (int nt = 0; nt < 4; ++nt)
      hf[kf][nt] = *(const bf16x8*)&h1[(nt * 16 + l15) * 136 + (kh * 2 + kf) * 32 + lhi * 8];

  f32x4 acc2[2][4] = {};

  auto loadA1 = [&](int m, bf16x8 (&wf)[2][2]) {
#pragma unroll
    for (int kf = 0; kf < 2; ++kf)
#pragma unroll
      for (int mt = 0; mt < 2; ++mt) {
        int o = rt * 32 + mt * 16 + l15;
        wf[kf][mt] = *(const bf16x8*)(w1p + ((m * 4 + kh * 2 + kf) * 128 + o) * 32 + lhi * 8);
      }
  };
  auto computeM = [&](int m, bf16x8 (&wf)[2][2]) {
    float xmv[4];
#pragma unroll
    for (int nt = 0; nt < 4; ++nt) xmv[nt] = (float)xs[(nt * 16 + l15) * 40 + m];
#pragma unroll
    for (int mt = 0; mt < 2; ++mt)
#pragma unroll
      for (int nt = 0; nt < 4; ++nt) {
        f32x4 Y = __builtin_amdgcn_mfma_f32_16x16x32_bf16(wf[0][mt], hf[0][nt],
                                                          (f32x4){0.f, 0.f, 0.f, 0.f}, 0, 0, 0);
        Y = __builtin_amdgcn_mfma_f32_16x16x32_bf16(wf[1][mt], hf[1][nt], Y, 0, 0, 0);
#pragma unroll
        for (int r = 0; r < 4; ++r) acc2[mt][nt][r] += xmv[nt] * Y[r];
      }
  };

  {
    bf16x8 wfA[2][2], wfB[2][2];
    loadA1(0, wfA);
    loadA1(1, wfB);
    for (int m = 0; m < 38; m += 2) {
      computeM(m, wfA);
      if (m + 2 < 39) loadA1(m + 2, wfA);
      computeM(m + 1, wfB);
      if (m + 3 < 39) loadA1(m + 3, wfB);
    }
    computeM(38, wfA);
  }

  // ---- combine K-halves via LDS: kh==1 writes, kh==0 adds ----
  __syncthreads();
  if (kh == 1) {
#pragma unroll
    for (int mt = 0; mt < 2; ++mt)
#pragma unroll
      for (int nt = 0; nt < 4; ++nt)
#pragma unroll
        for (int r = 0; r < 4; ++r) {
          int row = mt * 16 + lhi * 4 + r, c = nt * 16 + l15;
          red[(rt * 32 + row) * 65 + c] = acc2[mt][nt][r];
        }
  }
  __syncthreads();
  if (kh == 0) {
#pragma unroll
    for (int mt = 0; mt < 2; ++mt)
#pragma unroll
      for (int nt = 0; nt < 4; ++nt)
#pragma unroll
        for (int r = 0; r < 4; ++r) {
          int row = mt * 16 + lhi * 4 + r, c = nt * 16 + l15;
          acc2[mt][nt][r] += red[(rt * 32 + row) * 65 + c];
        }

    // ---- epilogue 1: bias+relu, d-sum -> out[ch 128..255]
#pragma unroll
    for (int mt = 0; mt < 2; ++mt) {
#pragma unroll
      for (int r = 0; r < 4; ++r) {
        int o = rt * 32 + mt * 16 + lhi * 4 + r;  // 0..127
        float bias = b1[o];
        float sb0 = 0.f, sb1 = 0.f;
#pragma unroll
        for (int nt = 0; nt < 4; ++nt) {
          float v = fmaxf(acc2[mt][nt][r] + bias, 0.f);
          v += __shfl_xor(v, 1); v += __shfl_xor(v, 2);
          v += __shfl_xor(v, 4); v += __shfl_xor(v, 8);
          if (nt < 2) sb0 += v; else sb1 += v;
        }
        if (l15 == 0) {
          out[(bb + 0) * 256 + 128 + o] = sb0;
          out[(bb + 1) * 256 + 128 + o] = sb1;
        }
      }
    }
  }
}

extern "C" void kernel_launch(void* const* d_in, const int* in_sizes, int n_in,
                              void* d_out, int out_size, void* d_ws, size_t ws_size,
                              hipStream_t stream) {
  const float* x  = (const float*)d_in[0];
  const float* w0 = (const float*)d_in[1];
  const float* b0 = (const float*)d_in[2];
  const float* w1 = (const float*)d_in[3];
  const float* b1 = (const float*)d_in[4];
  float* out = (float*)d_out;

  __bf16* w0b = (__bf16*)d_ws;                 // 50*256*32 bf16 = 819200 B
  __bf16* w1p = w0b + K0STEPS * 256 * 32;      // 39*4*128*32 bf16 = 1277952 B

  prep_kernel<<<256, 256, 0, stream>>>(w0, w1, w0b, w1p);
  cin_kernel<<<NBLK, THREADS, 0, stream>>>(x, w0b, b0, w1p, b1, out);
}

// Round 5
// 103.615 us; speedup vs baseline: 2.9381x; 2.9381x over previous
//
#include <hip/hip_runtime.h>

// CIN (xDeepFM) fused kernel for MI355X (gfx950), bf16 MFMA path, round 5.
// Same structure as round 4; ONLY change: __launch_bounds__(512, 2) so hipcc
// targets 2 blocks/CU (16 waves/CU, 4/SIMD) with a 128-VGPR cap instead of the
// 64-VGPR cap that (512,4) induced (spill -> 1.1 GB scratch traffic in r4).
// L0: M=256 split 8 waves x 32 rows; in-register z-frags; barrier-free K-loop.
// L1: reassociated out1[o,c] = sum_m x[m,c]*(W1_m @ h)[o,c]; 8 waves = 4 row-groups
//     x 2 K-halves (VGPR<=128); halves combined via LDS at the end.

typedef __bf16 bf16x8 __attribute__((ext_vector_type(8)));
typedef float f32x4 __attribute__((ext_vector_type(4)));

#define NB 2
#define NBLK 512
#define THREADS 512
#define K0STEPS 50   // 50*32 = 1600; rows with m==39 are zero-padded

__global__ __launch_bounds__(256) void prep_kernel(
    const float* __restrict__ w0, const float* __restrict__ w1,
    __bf16* __restrict__ w0b, __bf16* __restrict__ w1p) {
  int stride = gridDim.x * blockDim.x;
  int tid = blockIdx.x * blockDim.x + threadIdx.x;
  // w0b[blk][o][j]: K reordered as i' = m*40 + n (n<39 valid, else 0); i'>=1560 -> 0
  const int n0 = K0STEPS * 256 * 32;
  for (int idx = tid; idx < n0; idx += stride) {
    int j = idx & 31, o = (idx >> 5) & 255, blk = idx >> 13;
    int ip = blk * 32 + j;
    float v = 0.f;
    if (ip < 1560) {
      unsigned m = (unsigned)ip / 40u;
      unsigned n = (unsigned)ip - m * 40u;
      if (n < 39u) v = w0[o * 1521 + m * 39 + n];
    }
    w0b[idx] = (__bf16)v;
  }
  // w1p[((m*4+ks)*128 + o)*32 + j] = w1[o][m*128 + ks*32 + j]
  const int n1 = 39 * 4 * 128 * 32;
  for (int idx = tid; idx < n1; idx += stride) {
    int j = idx & 31, o = (idx >> 5) & 127, q = idx >> 12;
    int ks = q & 3, m = q >> 2;
    w1p[idx] = (__bf16)w1[o * 4992 + m * 128 + ks * 32 + j];
  }
}

__global__ __launch_bounds__(512, 2) void cin_kernel(
    const float* __restrict__ x,
    const __bf16* __restrict__ w0b, const float* __restrict__ b0,
    const __bf16* __restrict__ w1p, const float* __restrict__ b1,
    float* __restrict__ out) {
  // LDS: 5120 + 17408 + 33280 = 55808 B -> 2 blocks/CU
  __shared__ __align__(16) __bf16 xs[NB * 32 * 40];    // [c=(b,d)][40] (m=39 slot zero)
  __shared__ __align__(16) __bf16 h1[NB * 32 * 136];   // [c][136] h1a (bf16)
  __shared__ __align__(16) float red[4 * 32 * 65];     // K-half exchange, row pad 65

  const int t = threadIdx.x;
  const int bb = blockIdx.x * NB;
  const int w = t >> 6;          // wave id 0..7
  const int l15 = t & 15;
  const int lhi = (t >> 4) & 3;

  // ---- load x[b] -> xs transposed [c][m], bf16 ----
  for (int idx = t; idx < NB * 39 * 32; idx += THREADS) {
    int b = idx / 1248; int rem = idx - b * 1248;
    int m = rem >> 5; int d = rem & 31;
    xs[(b * 32 + d) * 40 + m] = (__bf16)x[(bb + b) * 1248 + rem];
  }
  if (t < NB * 32) xs[t * 40 + 39] = (__bf16)0.f;  // zero the m=39 pad
  __syncthreads();

  // ================= LAYER 0 (barrier-free K-loop, 32 rows/wave) =================
  f32x4 acc[2][4] = {};

  auto loadA0 = [&](int s, bf16x8 (&af)[2]) {
#pragma unroll
    for (int mt = 0; mt < 2; ++mt) {
      int o = w * 32 + mt * 16 + l15;
      af[mt] = *(const bf16x8*)(w0b + s * 8192 + o * 32 + lhi * 8);
    }
  };
  // per-wave in-register B fragments: bz[nt] holds z[k=i0..i0+7][c=nt*16+l15]
  auto zfr = [&](int s, bf16x8 (&bz)[4]) {
    unsigned i0 = (unsigned)(s * 32) + (unsigned)lhi * 8u;
    unsigned m = (i0 * 52429u) >> 21;   // i0/40 (exact for i0 < 2^16)
    unsigned nb = i0 - m * 40u;
#pragma unroll
    for (int nt = 0; nt < 4; ++nt) {
      int c = nt * 16 + l15;
      float xm = (float)xs[c * 40 + m];             // m==39 -> 0
      bf16x8 xn = *(const bf16x8*)&xs[c * 40 + nb]; // 16B-aligned
      bf16x8 vz;
#pragma unroll
      for (int j = 0; j < 8; ++j) vz[j] = (__bf16)(xm * (float)xn[j]);
      bz[nt] = vz;
    }
  };
  auto comp0 = [&](bf16x8 (&af)[2], bf16x8 (&bz)[4]) {
#pragma unroll
    for (int mt = 0; mt < 2; ++mt)
#pragma unroll
      for (int nt = 0; nt < 4; ++nt)
        acc[mt][nt] = __builtin_amdgcn_mfma_f32_16x16x32_bf16(af[mt], bz[nt], acc[mt][nt], 0, 0, 0);
  };

  {
    bf16x8 afA[2], afB[2];
    loadA0(0, afA);
    loadA0(1, afB);
    for (int s = 0; s < K0STEPS; s += 2) {
      bf16x8 bzA[4], bzB[4];
      zfr(s, bzA);
      comp0(afA, bzA);
      if (s + 2 < K0STEPS) loadA0(s + 2, afA);
      zfr(s + 1, bzB);
      comp0(afB, bzB);
      if (s + 3 < K0STEPS) loadA0(s + 3, afB);
    }
  }

  // ---- epilogue 0: bias+relu; o<128 -> h1a LDS; o>=128 -> d-sum -> out[ch 0..127]
  if (w < 4) {
#pragma unroll
    for (int mt = 0; mt < 2; ++mt) {
#pragma unroll
      for (int nt = 0; nt < 4; ++nt) {
        int c = nt * 16 + l15;
        int hbase = c * 136;
#pragma unroll
        for (int r = 0; r < 4; ++r) {
          int o = w * 32 + mt * 16 + lhi * 4 + r;
          float v = fmaxf(acc[mt][nt][r] + b0[o], 0.f);
          h1[hbase + o] = (__bf16)v;
        }
      }
    }
  } else {
#pragma unroll
    for (int mt = 0; mt < 2; ++mt) {
#pragma unroll
      for (int r = 0; r < 4; ++r) {
        int o = w * 32 + mt * 16 + lhi * 4 + r;  // 128..255
        float bias = b0[o];
        float sb0 = 0.f, sb1 = 0.f;
#pragma unroll
        for (int nt = 0; nt < 4; ++nt) {
          float v = fmaxf(acc[mt][nt][r] + bias, 0.f);
          v += __shfl_xor(v, 1); v += __shfl_xor(v, 2);
          v += __shfl_xor(v, 4); v += __shfl_xor(v, 8);
          if (nt < 2) sb0 += v; else sb1 += v;
        }
        if (l15 == 0) {
          out[(bb + 0) * 256 + (o - 128)] = sb0;
          out[(bb + 1) * 256 + (o - 128)] = sb1;
        }
      }
    }
  }
  __syncthreads();  // h1a visible to all waves

  // ============ LAYER 1 (reassociated; 4 row-groups x 2 K-halves) ============
  const int rt = w >> 1;   // row group: rows rt*32 .. rt*32+31
  const int kh = w & 1;    // K half: k in [kh*64, kh*64+64)

  // hf[kf][nt]: persistent B fragments of h for this K-half (32 VGPRs)
  bf16x8 hf[2][4];
#pragma unroll
  for (int kf = 0; kf < 2; ++kf)
#pragma unroll
    for (int nt = 0; nt < 4; ++nt)
      hf[kf][nt] = *(const bf16x8*)&h1[(nt * 16 + l15) * 136 + (kh * 2 + kf) * 32 + lhi * 8];

  f32x4 acc2[2][4] = {};

  auto loadA1 = [&](int m, bf16x8 (&wf)[2][2]) {
#pragma unroll
    for (int kf = 0; kf < 2; ++kf)
#pragma unroll
      for (int mt = 0; mt < 2; ++mt) {
        int o = rt * 32 + mt * 16 + l15;
        wf[kf][mt] = *(const bf16x8*)(w1p + ((m * 4 + kh * 2 + kf) * 128 + o) * 32 + lhi * 8);
      }
  };
  auto computeM = [&](int m, bf16x8 (&wf)[2][2]) {
    float xmv[4];
#pragma unroll
    for (int nt = 0; nt < 4; ++nt) xmv[nt] = (float)xs[(nt * 16 + l15) * 40 + m];
#pragma unroll
    for (int mt = 0; mt < 2; ++mt)
#pragma unroll
      for (int nt = 0; nt < 4; ++nt) {
        f32x4 Y = __builtin_amdgcn_mfma_f32_16x16x32_bf16(wf[0][mt], hf[0][nt],
                                                          (f32x4){0.f, 0.f, 0.f, 0.f}, 0, 0, 0);
        Y = __builtin_amdgcn_mfma_f32_16x16x32_bf16(wf[1][mt], hf[1][nt], Y, 0, 0, 0);
#pragma unroll
        for (int r = 0; r < 4; ++r) acc2[mt][nt][r] += xmv[nt] * Y[r];
      }
  };

  {
    bf16x8 wfA[2][2], wfB[2][2];
    loadA1(0, wfA);
    loadA1(1, wfB);
    for (int m = 0; m < 38; m += 2) {
      computeM(m, wfA);
      if (m + 2 < 39) loadA1(m + 2, wfA);
      computeM(m + 1, wfB);
      if (m + 3 < 39) loadA1(m + 3, wfB);
    }
    computeM(38, wfA);
  }

  // ---- combine K-halves via LDS: kh==1 writes, kh==0 adds ----
  __syncthreads();
  if (kh == 1) {
#pragma unroll
    for (int mt = 0; mt < 2; ++mt)
#pragma unroll
      for (int nt = 0; nt < 4; ++nt)
#pragma unroll
        for (int r = 0; r < 4; ++r) {
          int row = mt * 16 + lhi * 4 + r, c = nt * 16 + l15;
          red[(rt * 32 + row) * 65 + c] = acc2[mt][nt][r];
        }
  }
  __syncthreads();
  if (kh == 0) {
#pragma unroll
    for (int mt = 0; mt < 2; ++mt)
#pragma unroll
      for (int nt = 0; nt < 4; ++nt)
#pragma unroll
        for (int r = 0; r < 4; ++r) {
          int row = mt * 16 + lhi * 4 + r, c = nt * 16 + l15;
          acc2[mt][nt][r] += red[(rt * 32 + row) * 65 + c];
        }

    // ---- epilogue 1: bias+relu, d-sum -> out[ch 128..255]
#pragma unroll
    for (int mt = 0; mt < 2; ++mt) {
#pragma unroll
      for (int r = 0; r < 4; ++r) {
        int o = rt * 32 + mt * 16 + lhi * 4 + r;  // 0..127
        float bias = b1[o];
        float sb0 = 0.f, sb1 = 0.f;
#pragma unroll
        for (int nt = 0; nt < 4; ++nt) {
          float v = fmaxf(acc2[mt][nt][r] + bias, 0.f);
          v += __shfl_xor(v, 1); v += __shfl_xor(v, 2);
          v += __shfl_xor(v, 4); v += __shfl_xor(v, 8);
          if (nt < 2) sb0 += v; else sb1 += v;
        }
        if (l15 == 0) {
          out[(bb + 0) * 256 + 128 + o] = sb0;
          out[(bb + 1) * 256 + 128 + o] = sb1;
        }
      }
    }
  }
}

extern "C" void kernel_launch(void* const* d_in, const int* in_sizes, int n_in,
                              void* d_out, int out_size, void* d_ws, size_t ws_size,
                              hipStream_t stream) {
  const float* x  = (const float*)d_in[0];
  const float* w0 = (const float*)d_in[1];
  const float* b0 = (const float*)d_in[2];
  const float* w1 = (const float*)d_in[3];
  const float* b1 = (const float*)d_in[4];
  float* out = (float*)d_out;

  __bf16* w0b = (__bf16*)d_ws;                 // 50*256*32 bf16 = 819200 B
  __bf16* w1p = w0b + K0STEPS * 256 * 32;      // 39*4*128*32 bf16 = 1277952 B

  prep_kernel<<<256, 256, 0, stream>>>(w0, w1, w0b, w1p);
  cin_kernel<<<NBLK, THREADS, 0, stream>>>(x, w0b, b0, w1p, b1, out);
}

// Round 6
// 103.546 us; speedup vs baseline: 2.9401x; 1.0007x over previous
//
#include <hip/hip_runtime.h>

// CIN (xDeepFM) fused kernel for MI355X (gfx950), bf16 MFMA path, round 6.
// Theory: weight stream is the binder. Changes vs r5:
//  - wave-dense weight layout: each wave's per-step fragment loads are one
//    contiguous 1KB (L0) / 4KB (L1) block -> full 128B L2-line utilization.
//  - branchless deep prefetch: L0 4-deep rotating named buffers, L1 2-deep,
//    with zero-padded weight arrays (52 L0 steps, 42 L1 m-steps) so no guards.
// L0: M=256, 8 waves x 32 rows, in-register z-frags, barrier-free.
// L1: reassociated out1[o,c] = sum_m x[m,c]*(W1_m @ h)[o,c]; 4 row-groups x
//     2 K-halves; halves combined via LDS.

typedef __bf16 bf16x8 __attribute__((ext_vector_type(8)));
typedef float f32x4 __attribute__((ext_vector_type(4)));

#define NB 2
#define NBLK 512
#define THREADS 512
#define K0C 50   // L0 compute steps (50*32 = 1600 >= 39*40)
#define K0P 52   // L0 padded steps (prefetch overrun, zero weights)
#define M1C 40   // L1 compute m-steps (m=39 contributes exactly 0)
#define M1P 42   // L1 padded m-steps

__global__ __launch_bounds__(256) void prep_kernel(
    const float* __restrict__ w0, const float* __restrict__ w1,
    __bf16* __restrict__ w0c, __bf16* __restrict__ w1c) {
  int stride = gridDim.x * blockDim.x;
  int tid = blockIdx.x * blockDim.x + threadIdx.x;
  // w0c: [s<52][w<8][mt<2][l15<16][lhi<4][j<8]; row o=w*32+mt*16+l15,
  //      k-index ip = s*32+lhi*8+j with reorder i' = m*40+n (n<39 valid).
  const int n0 = K0P * 8192;
  for (int idx = tid; idx < n0; idx += stride) {
    int j = idx & 7, lhi = (idx >> 3) & 3, l15 = (idx >> 5) & 15;
    int mt = (idx >> 9) & 1, w8 = (idx >> 10) & 7, s = idx >> 13;
    int o = w8 * 32 + mt * 16 + l15;
    int ip = s * 32 + lhi * 8 + j;
    float v = 0.f;
    if (ip < 1560) {
      unsigned m = (unsigned)ip / 40u;
      unsigned n = (unsigned)ip - m * 40u;
      if (n < 39u) v = w0[o * 1521 + m * 39 + n];
    }
    w0c[idx] = (__bf16)v;
  }
  // w1c: [m<42][kh<2][rt<4][kf<2][mt<2][l15<16][lhi<4][j<8];
  //      row o=rt*32+mt*16+l15, k = kh*64+kf*32+lhi*8+j (within W1_m).
  const int n1 = M1P * 16384;
  for (int idx = tid; idx < n1; idx += stride) {
    int j = idx & 7, lhi = (idx >> 3) & 3, l15 = (idx >> 5) & 15;
    int mt = (idx >> 9) & 1, kf = (idx >> 10) & 1, rt = (idx >> 11) & 3;
    int kh = (idx >> 13) & 1, m = idx >> 14;
    int o = rt * 32 + mt * 16 + l15;
    int k = kh * 64 + kf * 32 + lhi * 8 + j;
    float v = (m < 39) ? w1[o * 4992 + m * 128 + k] : 0.f;
    w1c[idx] = (__bf16)v;
  }
}

__global__ __launch_bounds__(512, 2) void cin_kernel(
    const float* __restrict__ x,
    const __bf16* __restrict__ w0c, const float* __restrict__ b0,
    const __bf16* __restrict__ w1c, const float* __restrict__ b1,
    float* __restrict__ out) {
  // LDS: 5120 + 17408 + 33280 = 55808 B -> 2 blocks/CU
  __shared__ __align__(16) __bf16 xs[NB * 32 * 40];    // [c=(b,d)][40] (m=39 slot zero)
  __shared__ __align__(16) __bf16 h1[NB * 32 * 136];   // [c][136] h1a (bf16)
  __shared__ __align__(16) float red[4 * 32 * 65];     // K-half exchange, row pad 65

  const int t = threadIdx.x;
  const int bb = blockIdx.x * NB;
  const int w = t >> 6;          // wave id 0..7
  const int l15 = t & 15;
  const int lhi = (t >> 4) & 3;
  const int lane_off = ((l15 << 2) | lhi) << 3;  // element offset in 1KB chunk

  // ---- load x[b] -> xs transposed [c][m], bf16 ----
  for (int idx = t; idx < NB * 39 * 32; idx += THREADS) {
    int b = idx / 1248; int rem = idx - b * 1248;
    int m = rem >> 5; int d = rem & 31;
    xs[(b * 32 + d) * 40 + m] = (__bf16)x[(bb + b) * 1248 + rem];
  }
  if (t < NB * 32) xs[t * 40 + 39] = (__bf16)0.f;  // zero the m=39 pad
  __syncthreads();

  // ================= LAYER 0 (barrier-free K-loop, 32 rows/wave) =================
  f32x4 acc[2][4] = {};
  const __bf16* p0 = w0c + w * 1024 + lane_off;

  auto loadA0 = [&](int s, bf16x8 (&af)[2]) {
    const __bf16* p = p0 + s * 8192;
    af[0] = *(const bf16x8*)(p);
    af[1] = *(const bf16x8*)(p + 512);
  };
  // per-wave in-register B fragments: bz[nt] holds z[k=i0..i0+7][c=nt*16+l15]
  auto zfr = [&](int s, bf16x8 (&bz)[4]) {
    unsigned i0 = (unsigned)(s * 32) + (unsigned)lhi * 8u;
    unsigned m = (i0 * 52429u) >> 21;   // i0/40 (exact for i0 < 2^16)
    unsigned nb = i0 - m * 40u;
#pragma unroll
    for (int nt = 0; nt < 4; ++nt) {
      int c = nt * 16 + l15;
      float xm = (float)xs[c * 40 + m];             // m==39 -> 0
      bf16x8 xn = *(const bf16x8*)&xs[c * 40 + nb]; // 16B-aligned
      bf16x8 vz;
#pragma unroll
      for (int j = 0; j < 8; ++j) vz[j] = (__bf16)(xm * (float)xn[j]);
      bz[nt] = vz;
    }
  };
  auto comp0 = [&](bf16x8 (&af)[2], bf16x8 (&bz)[4]) {
#pragma unroll
    for (int mt = 0; mt < 2; ++mt)
#pragma unroll
      for (int nt = 0; nt < 4; ++nt)
        acc[mt][nt] = __builtin_amdgcn_mfma_f32_16x16x32_bf16(af[mt], bz[nt], acc[mt][nt], 0, 0, 0);
  };

  {
    bf16x8 af0[2], af1[2], af2[2], af3[2];
    loadA0(0, af0); loadA0(1, af1); loadA0(2, af2); loadA0(3, af3);
    for (int s = 0; s < 48; s += 4) {
      bf16x8 bz[4];
      zfr(s + 0, bz); comp0(af0, bz); loadA0(s + 4, af0);
      zfr(s + 1, bz); comp0(af1, bz); loadA0(s + 5, af1);
      zfr(s + 2, bz); comp0(af2, bz); loadA0(s + 6, af2);
      zfr(s + 3, bz); comp0(af3, bz); loadA0(s + 7, af3);
    }
    bf16x8 bz[4];
    zfr(48, bz); comp0(af0, bz);
    zfr(49, bz); comp0(af1, bz);
  }

  // ---- epilogue 0: bias+relu; o<128 -> h1a LDS; o>=128 -> d-sum -> out[ch 0..127]
  if (w < 4) {
#pragma unroll
    for (int mt = 0; mt < 2; ++mt) {
#pragma unroll
      for (int nt = 0; nt < 4; ++nt) {
        int c = nt * 16 + l15;
        int hbase = c * 136;
#pragma unroll
        for (int r = 0; r < 4; ++r) {
          int o = w * 32 + mt * 16 + lhi * 4 + r;
          float v = fmaxf(acc[mt][nt][r] + b0[o], 0.f);
          h1[hbase + o] = (__bf16)v;
        }
      }
    }
  } else {
#pragma unroll
    for (int mt = 0; mt < 2; ++mt) {
#pragma unroll
      for (int r = 0; r < 4; ++r) {
        int o = w * 32 + mt * 16 + lhi * 4 + r;  // 128..255
        float bias = b0[o];
        float sb0 = 0.f, sb1 = 0.f;
#pragma unroll
        for (int nt = 0; nt < 4; ++nt) {
          float v = fmaxf(acc[mt][nt][r] + bias, 0.f);
          v += __shfl_xor(v, 1); v += __shfl_xor(v, 2);
          v += __shfl_xor(v, 4); v += __shfl_xor(v, 8);
          if (nt < 2) sb0 += v; else sb1 += v;
        }
        if (l15 == 0) {
          out[(bb + 0) * 256 + (o - 128)] = sb0;
          out[(bb + 1) * 256 + (o - 128)] = sb1;
        }
      }
    }
  }
  __syncthreads();  // h1a visible to all waves

  // ============ LAYER 1 (reassociated; 4 row-groups x 2 K-halves) ============
  const int rt = w >> 1;   // row group: rows rt*32 .. rt*32+31
  const int kh = w & 1;    // K half: k in [kh*64, kh*64+64)

  // hf[kf][nt]: persistent B fragments of h for this K-half (32 VGPRs)
  bf16x8 hf[2][4];
#pragma unroll
  for (int kf = 0; kf < 2; ++kf)
#pragma unroll
    for (int nt = 0; nt < 4; ++nt)
      hf[kf][nt] = *(const bf16x8*)&h1[(nt * 16 + l15) * 136 + (kh * 2 + kf) * 32 + lhi * 8];

  f32x4 acc2[2][4] = {};
  const __bf16* p1 = w1c + (kh * 4 + rt) * 2048 + lane_off;

  auto loadA1 = [&](int m, bf16x8 (&wf)[2][2]) {
    const __bf16* p = p1 + m * 16384;
    wf[0][0] = *(const bf16x8*)(p);
    wf[0][1] = *(const bf16x8*)(p + 512);
    wf[1][0] = *(const bf16x8*)(p + 1024);
    wf[1][1] = *(const bf16x8*)(p + 1536);
  };
  auto computeM = [&](int m, bf16x8 (&wf)[2][2]) {
    float xmv[4];
#pragma unroll
    for (int nt = 0; nt < 4; ++nt) xmv[nt] = (float)xs[(nt * 16 + l15) * 40 + m];
#pragma unroll
    for (int mt = 0; mt < 2; ++mt)
#pragma unroll
      for (int nt = 0; nt < 4; ++nt) {
        f32x4 Y = __builtin_amdgcn_mfma_f32_16x16x32_bf16(wf[0][mt], hf[0][nt],
                                                          (f32x4){0.f, 0.f, 0.f, 0.f}, 0, 0, 0);
        Y = __builtin_amdgcn_mfma_f32_16x16x32_bf16(wf[1][mt], hf[1][nt], Y, 0, 0, 0);
#pragma unroll
        for (int r = 0; r < 4; ++r) acc2[mt][nt][r] += xmv[nt] * Y[r];
      }
  };

  {
    bf16x8 wfA[2][2], wfB[2][2];
    loadA1(0, wfA);
    loadA1(1, wfB);
    for (int m = 0; m < M1C; m += 2) {
      computeM(m, wfA);     loadA1(m + 2, wfA);   // max index M1C+1 = 41 < M1P
      computeM(m + 1, wfB); loadA1(m + 3, wfB);
    }
  }

  // ---- combine K-halves via LDS: kh==1 writes, kh==0 adds ----
  __syncthreads();
  if (kh == 1) {
#pragma unroll
    for (int mt = 0; mt < 2; ++mt)
#pragma unroll
      for (int nt = 0; nt < 4; ++nt)
#pragma unroll
        for (int r = 0; r < 4; ++r) {
          int row = mt * 16 + lhi * 4 + r, c = nt * 16 + l15;
          red[(rt * 32 + row) * 65 + c] = acc2[mt][nt][r];
        }
  }
  __syncthreads();
  if (kh == 0) {
#pragma unroll
    for (int mt = 0; mt < 2; ++mt)
#pragma unroll
      for (int nt = 0; nt < 4; ++nt)
#pragma unroll
        for (int r = 0; r < 4; ++r) {
          int row = mt * 16 + lhi * 4 + r, c = nt * 16 + l15;
          acc2[mt][nt][r] += red[(rt * 32 + row) * 65 + c];
        }

    // ---- epilogue 1: bias+relu, d-sum -> out[ch 128..255]
#pragma unroll
    for (int mt = 0; mt < 2; ++mt) {
#pragma unroll
      for (int r = 0; r < 4; ++r) {
        int o = rt * 32 + mt * 16 + lhi * 4 + r;  // 0..127
        float bias = b1[o];
        float sb0 = 0.f, sb1 = 0.f;
#pragma unroll
        for (int nt = 0; nt < 4; ++nt) {
          float v = fmaxf(acc2[mt][nt][r] + bias, 0.f);
          v += __shfl_xor(v, 1); v += __shfl_xor(v, 2);
          v += __shfl_xor(v, 4); v += __shfl_xor(v, 8);
          if (nt < 2) sb0 += v; else sb1 += v;
        }
        if (l15 == 0) {
          out[(bb + 0) * 256 + 128 + o] = sb0;
          out[(bb + 1) * 256 + 128 + o] = sb1;
        }
      }
    }
  }
}

extern "C" void kernel_launch(void* const* d_in, const int* in_sizes, int n_in,
                              void* d_out, int out_size, void* d_ws, size_t ws_size,
                              hipStream_t stream) {
  const float* x  = (const float*)d_in[0];
  const float* w0 = (const float*)d_in[1];
  const float* b0 = (const float*)d_in[2];
  const float* w1 = (const float*)d_in[3];
  const float* b1 = (const float*)d_in[4];
  float* out = (float*)d_out;

  __bf16* w0c = (__bf16*)d_ws;                 // 52*8192  bf16 = 851968 B
  __bf16* w1c = w0c + K0P * 8192;              // 42*16384 bf16 = 1376256 B

  prep_kernel<<<256, 256, 0, stream>>>(w0, w1, w0c, w1c);
  cin_kernel<<<NBLK, THREADS, 0, stream>>>(x, w0c, b0, w1c, b1, out);
}

// Round 7
// 84.030 us; speedup vs baseline: 3.6230x; 1.2323x over previous
//
#include <hip/hip_runtime.h>

// CIN (xDeepFM) fused kernel for MI355X (gfx950), round 7: f16 datapath.
// Theory: VALU pipe (z-gen bf16 cvt chains, duplicated per wave) is the binder.
// Change vs r6: bf16 -> _Float16 everywhere; z-gen via packed v_pk_mul_f16
// (no conversions); mfma_f32_16x16x32_f16; vectorized f32x4 epilogue FMA.
// Schedule/layout/occupancy identical to r6.

typedef _Float16 f16x8 __attribute__((ext_vector_type(8)));
typedef float f32x4 __attribute__((ext_vector_type(4)));

#define NB 2
#define NBLK 512
#define THREADS 512
#define K0C 50   // L0 compute steps (50*32 = 1600 >= 39*40)
#define K0P 52   // L0 padded steps (prefetch overrun, zero weights)
#define M1C 40   // L1 compute m-steps (m=39 contributes exactly 0)
#define M1P 42   // L1 padded m-steps

__global__ __launch_bounds__(256) void prep_kernel(
    const float* __restrict__ w0, const float* __restrict__ w1,
    _Float16* __restrict__ w0c, _Float16* __restrict__ w1c) {
  int stride = gridDim.x * blockDim.x;
  int tid = blockIdx.x * blockDim.x + threadIdx.x;
  // w0c: [s<52][w<8][mt<2][l15<16][lhi<4][j<8]; row o=w*32+mt*16+l15,
  //      k-index ip = s*32+lhi*8+j with reorder i' = m*40+n (n<39 valid).
  const int n0 = K0P * 8192;
  for (int idx = tid; idx < n0; idx += stride) {
    int j = idx & 7, lhi = (idx >> 3) & 3, l15 = (idx >> 5) & 15;
    int mt = (idx >> 9) & 1, w8 = (idx >> 10) & 7, s = idx >> 13;
    int o = w8 * 32 + mt * 16 + l15;
    int ip = s * 32 + lhi * 8 + j;
    float v = 0.f;
    if (ip < 1560) {
      unsigned m = (unsigned)ip / 40u;
      unsigned n = (unsigned)ip - m * 40u;
      if (n < 39u) v = w0[o * 1521 + m * 39 + n];
    }
    w0c[idx] = (_Float16)v;
  }
  // w1c: [m<42][kh<2][rt<4][kf<2][mt<2][l15<16][lhi<4][j<8];
  //      row o=rt*32+mt*16+l15, k = kh*64+kf*32+lhi*8+j (within W1_m).
  const int n1 = M1P * 16384;
  for (int idx = tid; idx < n1; idx += stride) {
    int j = idx & 7, lhi = (idx >> 3) & 3, l15 = (idx >> 5) & 15;
    int mt = (idx >> 9) & 1, kf = (idx >> 10) & 1, rt = (idx >> 11) & 3;
    int kh = (idx >> 13) & 1, m = idx >> 14;
    int o = rt * 32 + mt * 16 + l15;
    int k = kh * 64 + kf * 32 + lhi * 8 + j;
    float v = (m < 39) ? w1[o * 4992 + m * 128 + k] : 0.f;
    w1c[idx] = (_Float16)v;
  }
}

__global__ __launch_bounds__(512, 2) void cin_kernel(
    const float* __restrict__ x,
    const _Float16* __restrict__ w0c, const float* __restrict__ b0,
    const _Float16* __restrict__ w1c, const float* __restrict__ b1,
    float* __restrict__ out) {
  // LDS: 5120 + 17408 + 33280 = 55808 B -> 2 blocks/CU
  __shared__ __align__(16) _Float16 xs[NB * 32 * 40];    // [c=(b,d)][40] (m=39 slot zero)
  __shared__ __align__(16) _Float16 h1[NB * 32 * 136];   // [c][136] h1a (f16)
  __shared__ __align__(16) float red[4 * 32 * 65];       // K-half exchange, row pad 65

  const int t = threadIdx.x;
  const int bb = blockIdx.x * NB;
  const int w = t >> 6;          // wave id 0..7
  const int l15 = t & 15;
  const int lhi = (t >> 4) & 3;
  const int lane_off = ((l15 << 2) | lhi) << 3;  // element offset in 1KB chunk

  // ---- load x[b] -> xs transposed [c][m], f16 ----
  for (int idx = t; idx < NB * 39 * 32; idx += THREADS) {
    int b = idx / 1248; int rem = idx - b * 1248;
    int m = rem >> 5; int d = rem & 31;
    xs[(b * 32 + d) * 40 + m] = (_Float16)x[(bb + b) * 1248 + rem];
  }
  if (t < NB * 32) xs[t * 40 + 39] = (_Float16)0.f;  // zero the m=39 pad
  __syncthreads();

  // ================= LAYER 0 (barrier-free K-loop, 32 rows/wave) =================
  f32x4 acc[2][4] = {};
  const _Float16* p0 = w0c + w * 1024 + lane_off;

  auto loadA0 = [&](int s, f16x8 (&af)[2]) {
    const _Float16* p = p0 + s * 8192;
    af[0] = *(const f16x8*)(p);
    af[1] = *(const f16x8*)(p + 512);
  };
  // per-wave in-register B fragments: bz[nt] = z[k=i0..i0+7][c=nt*16+l15]
  // packed f16 multiply: 4x v_pk_mul_f16 per fragment, zero conversions.
  auto zfr = [&](int s, f16x8 (&bz)[4]) {
    unsigned i0 = (unsigned)(s * 32) + (unsigned)lhi * 8u;
    unsigned m = (i0 * 52429u) >> 21;   // i0/40 (exact for i0 < 2^16)
    unsigned nb = i0 - m * 40u;
#pragma unroll
    for (int nt = 0; nt < 4; ++nt) {
      int c = nt * 16 + l15;
      _Float16 xm = xs[c * 40 + m];                 // m==39 -> 0
      f16x8 xn = *(const f16x8*)&xs[c * 40 + nb];   // 16B-aligned
      bz[nt] = xn * xm;                             // splat + 4x v_pk_mul_f16
    }
  };
  auto comp0 = [&](f16x8 (&af)[2], f16x8 (&bz)[4]) {
#pragma unroll
    for (int mt = 0; mt < 2; ++mt)
#pragma unroll
      for (int nt = 0; nt < 4; ++nt)
        acc[mt][nt] = __builtin_amdgcn_mfma_f32_16x16x32_f16(af[mt], bz[nt], acc[mt][nt], 0, 0, 0);
  };

  {
    f16x8 af0[2], af1[2], af2[2], af3[2];
    loadA0(0, af0); loadA0(1, af1); loadA0(2, af2); loadA0(3, af3);
    for (int s = 0; s < 48; s += 4) {
      f16x8 bz[4];
      zfr(s + 0, bz); comp0(af0, bz); loadA0(s + 4, af0);
      zfr(s + 1, bz); comp0(af1, bz); loadA0(s + 5, af1);
      zfr(s + 2, bz); comp0(af2, bz); loadA0(s + 6, af2);
      zfr(s + 3, bz); comp0(af3, bz); loadA0(s + 7, af3);
    }
    f16x8 bz[4];
    zfr(48, bz); comp0(af0, bz);
    zfr(49, bz); comp0(af1, bz);
  }

  // ---- epilogue 0: bias+relu; o<128 -> h1a LDS; o>=128 -> d-sum -> out[ch 0..127]
  if (w < 4) {
#pragma unroll
    for (int mt = 0; mt < 2; ++mt) {
#pragma unroll
      for (int nt = 0; nt < 4; ++nt) {
        int c = nt * 16 + l15;
        int hbase = c * 136;
#pragma unroll
        for (int r = 0; r < 4; ++r) {
          int o = w * 32 + mt * 16 + lhi * 4 + r;
          float v = fmaxf(acc[mt][nt][r] + b0[o], 0.f);
          h1[hbase + o] = (_Float16)v;
        }
      }
    }
  } else {
#pragma unroll
    for (int mt = 0; mt < 2; ++mt) {
#pragma unroll
      for (int r = 0; r < 4; ++r) {
        int o = w * 32 + mt * 16 + lhi * 4 + r;  // 128..255
        float bias = b0[o];
        float sb0 = 0.f, sb1 = 0.f;
#pragma unroll
        for (int nt = 0; nt < 4; ++nt) {
          float v = fmaxf(acc[mt][nt][r] + bias, 0.f);
          v += __shfl_xor(v, 1); v += __shfl_xor(v, 2);
          v += __shfl_xor(v, 4); v += __shfl_xor(v, 8);
          if (nt < 2) sb0 += v; else sb1 += v;
        }
        if (l15 == 0) {
          out[(bb + 0) * 256 + (o - 128)] = sb0;
          out[(bb + 1) * 256 + (o - 128)] = sb1;
        }
      }
    }
  }
  __syncthreads();  // h1a visible to all waves

  // ============ LAYER 1 (reassociated; 4 row-groups x 2 K-halves) ============
  const int rt = w >> 1;   // row group: rows rt*32 .. rt*32+31
  const int kh = w & 1;    // K half: k in [kh*64, kh*64+64)

  // hf[kf][nt]: persistent B fragments of h for this K-half (32 VGPRs)
  f16x8 hf[2][4];
#pragma unroll
  for (int kf = 0; kf < 2; ++kf)
#pragma unroll
    for (int nt = 0; nt < 4; ++nt)
      hf[kf][nt] = *(const f16x8*)&h1[(nt * 16 + l15) * 136 + (kh * 2 + kf) * 32 + lhi * 8];

  f32x4 acc2[2][4] = {};
  const _Float16* p1 = w1c + (kh * 4 + rt) * 2048 + lane_off;

  auto loadA1 = [&](int m, f16x8 (&wf)[2][2]) {
    const _Float16* p = p1 + m * 16384;
    wf[0][0] = *(const f16x8*)(p);
    wf[0][1] = *(const f16x8*)(p + 512);
    wf[1][0] = *(const f16x8*)(p + 1024);
    wf[1][1] = *(const f16x8*)(p + 1536);
  };
  auto computeM = [&](int m, f16x8 (&wf)[2][2]) {
    float xmv[4];
#pragma unroll
    for (int nt = 0; nt < 4; ++nt) xmv[nt] = (float)xs[(nt * 16 + l15) * 40 + m];
#pragma unroll
    for (int mt = 0; mt < 2; ++mt)
#pragma unroll
      for (int nt = 0; nt < 4; ++nt) {
        f32x4 Y = __builtin_amdgcn_mfma_f32_16x16x32_f16(wf[0][mt], hf[0][nt],
                                                         (f32x4){0.f, 0.f, 0.f, 0.f}, 0, 0, 0);
        Y = __builtin_amdgcn_mfma_f32_16x16x32_f16(wf[1][mt], hf[1][nt], Y, 0, 0, 0);
        acc2[mt][nt] += Y * xmv[nt];   // vectorized -> v_pk_fma_f32
      }
  };

  {
    f16x8 wfA[2][2], wfB[2][2];
    loadA1(0, wfA);
    loadA1(1, wfB);
    for (int m = 0; m < M1C; m += 2) {
      computeM(m, wfA);     loadA1(m + 2, wfA);   // max index M1C+1 = 41 < M1P
      computeM(m + 1, wfB); loadA1(m + 3, wfB);
    }
  }

  // ---- combine K-halves via LDS: kh==1 writes, kh==0 adds ----
  __syncthreads();
  if (kh == 1) {
#pragma unroll
    for (int mt = 0; mt < 2; ++mt)
#pragma unroll
      for (int nt = 0; nt < 4; ++nt)
#pragma unroll
        for (int r = 0; r < 4; ++r) {
          int row = mt * 16 + lhi * 4 + r, c = nt * 16 + l15;
          red[(rt * 32 + row) * 65 + c] = acc2[mt][nt][r];
        }
  }
  __syncthreads();
  if (kh == 0) {
#pragma unroll
    for (int mt = 0; mt < 2; ++mt)
#pragma unroll
      for (int nt = 0; nt < 4; ++nt)
#pragma unroll
        for (int r = 0; r < 4; ++r) {
          int row = mt * 16 + lhi * 4 + r, c = nt * 16 + l15;
          acc2[mt][nt][r] += red[(rt * 32 + row) * 65 + c];
        }

    // ---- epilogue 1: bias+relu, d-sum -> out[ch 128..255]
#pragma unroll
    for (int mt = 0; mt < 2; ++mt) {
#pragma unroll
      for (int r = 0; r < 4; ++r) {
        int o = rt * 32 + mt * 16 + lhi * 4 + r;  // 0..127
        float bias = b1[o];
        float sb0 = 0.f, sb1 = 0.f;
#pragma unroll
        for (int nt = 0; nt < 4; ++nt) {
          float v = fmaxf(acc2[mt][nt][r] + bias, 0.f);
          v += __shfl_xor(v, 1); v += __shfl_xor(v, 2);
          v += __shfl_xor(v, 4); v += __shfl_xor(v, 8);
          if (nt < 2) sb0 += v; else sb1 += v;
        }
        if (l15 == 0) {
          out[(bb + 0) * 256 + 128 + o] = sb0;
          out[(bb + 1) * 256 + 128 + o] = sb1;
        }
      }
    }
  }
}

extern "C" void kernel_launch(void* const* d_in, const int* in_sizes, int n_in,
                              void* d_out, int out_size, void* d_ws, size_t ws_size,
                              hipStream_t stream) {
  const float* x  = (const float*)d_in[0];
  const float* w0 = (const float*)d_in[1];
  const float* b0 = (const float*)d_in[2];
  const float* w1 = (const float*)d_in[3];
  const float* b1 = (const float*)d_in[4];
  float* out = (float*)d_out;

  _Float16* w0c = (_Float16*)d_ws;             // 52*8192  f16 = 851968 B
  _Float16* w1c = w0c + K0P * 8192;            // 42*16384 f16 = 1376256 B

  prep_kernel<<<256, 256, 0, stream>>>(w0, w1, w0c, w1c);
  cin_kernel<<<NBLK, THREADS, 0, stream>>>(x, w0c, b0, w1c, b1, out);
}